// Round 10
// baseline (843.559 us; speedup 1.0000x reference)
//
#include <hip/hip_runtime.h>
#include <hip/hip_bf16.h>
#include <math.h>

#define N_BATCH 2048
#define T_STEPS 50
#define NCODES  40
#define MH      526
#define AUXD    10
#define WLROWS  536    // MH + AUXD
#define E_DIM   256
#define G_DIM   1024   // 4*E
#define BM      16     // batch rows per recurrence block
#define TCHUNK  10     // time steps per chunk (5 chunks)
#define MBLK    64     // (n,t) rows per fused block

typedef __attribute__((ext_vector_type(8))) short short8;   // 8 bf16 = 4 VGPR
typedef __attribute__((ext_vector_type(4))) short short4v;  // 4 bf16 = 2 VGPR
typedef __attribute__((ext_vector_type(4))) float f32x4;

__device__ __forceinline__ short f2bf(float f) {
    __hip_bfloat16 h = __float2bfloat16(f);
    return *reinterpret_cast<short*>(&h);
}
__device__ __forceinline__ float bf2f(unsigned short u) {
    return __uint_as_float(((unsigned int)u) << 16);
}
__device__ __forceinline__ float sigf(float x) {
    return 1.f / (1.f + __expf(-x));
}
__device__ __forceinline__ float tanhfast(float x) {
    return 2.f / (1.f + __expf(-2.f * x)) - 1.f;
}

// ---------------------------------------------------------------------------
// Wrec (R for k_rec), R7 layout: fg = (kk*8 + j8)*8 + w ; j8 = eb*4 + g
//   Wrec[fg*512 + lane*8 + j] = R[kk*32 + p*8 + j][g*256 + w*32 + eb*16 + lr]
// ---------------------------------------------------------------------------
__global__ __launch_bounds__(256) void k_prep_wrec(
    const float* __restrict__ R, short* __restrict__ Wrec)
{
    const int gid  = blockIdx.x * 256 + threadIdx.x;   // 32768
    const int fg   = gid >> 6, lane = gid & 63;
    const int p    = lane >> 4, lr = lane & 15;
    const int kk   = fg >> 6;
    const int j8   = (fg >> 3) & 7;
    const int w    = fg & 7;
    const int eb   = j8 >> 2, g = j8 & 3;
    const int n    = g * 256 + w * 32 + eb * 16 + lr;
    short* dst = Wrec + (size_t)fg * 512 + lane * 8;
    #pragma unroll
    for (int j = 0; j < 8; ++j)
        dst[j] = f2bf(R[(size_t)(kk * 32 + p * 8 + j) * G_DIM + n]);
}

// WfK (K for k_fused phase 3): fg = (kb*8 + cb)*8 + w
__global__ __launch_bounds__(256) void k_prep_wfk(
    const float* __restrict__ K, short* __restrict__ WfK)
{
    const int gid  = blockIdx.x * 256 + threadIdx.x;   // 32768
    const int fg   = gid >> 6, lane = gid & 63;
    const int p    = lane >> 4, lr = lane & 15;
    const int kb   = fg >> 6;
    const int cb   = (fg >> 3) & 7;
    const int w    = fg & 7;
    const int n    = w * 128 + cb * 16 + lr;
    short* dst = WfK + (size_t)fg * 512 + lane * 8;
    #pragma unroll
    for (int j = 0; j < 8; ++j)
        dst[j] = f2bf(K[(size_t)(kb * 32 + p * 8 + j) * G_DIM + n]);
}

// WfL (W_lin for k_fused phase 2): fg = (kk*2 + cb)*8 + w, kk 0..16
__global__ __launch_bounds__(256) void k_prep_wfl(
    const float* __restrict__ W_lin, short* __restrict__ WfL)
{
    const int gid  = blockIdx.x * 256 + threadIdx.x;   // 17408
    const int fg   = gid >> 6, lane = gid & 63;
    const int p    = lane >> 4, lr = lane & 15;
    const int kk   = fg >> 4;
    const int cb   = (fg >> 3) & 1;
    const int w    = fg & 7;
    const int n    = w * 32 + cb * 16 + lr;
    short* dst = WfL + (size_t)fg * 512 + lane * 8;
    #pragma unroll
    for (int j = 0; j < 8; ++j) {
        const int k = kk * 32 + p * 8 + j;
        dst[j] = (k < WLROWS) ? f2bf(W_lin[(size_t)k * E_DIM + n]) : (short)0;
    }
}

// ---------------------------------------------------------------------------
// Fused embed + xz GEMM, tl-major, 64 rows/block (grid = TCHUNK*32).
// Output in k_rec (R7) fragment order:
//   idx = ((rgg*TCHUNK + tl)*64 + wp*8 + j8)*256 + lane*4
// where rgg = global 16-row group, c0 = col base:
//   g = c0>>8, wp = (c0>>5)&7, eb = (c0>>4)&1, j8 = eb*4 + g.
// ---------------------------------------------------------------------------
__global__ __launch_bounds__(512, 1) void k_fused(
    const int* __restrict__ code, const float* __restrict__ aux,
    const short* __restrict__ WfL, const float* __restrict__ b_lin,
    const short* __restrict__ WfK, short* __restrict__ xzp, int t0)
{
    const int tid  = threadIdx.x;
    const int w    = tid >> 6;
    const int lane = tid & 63;
    const int lr   = lane & 15;
    const int p    = lane >> 4;
    const int tl   = blockIdx.x >> 5;          // 0..TCHUNK-1
    const int ngg  = blockIdx.x & 31;
    const int n0   = ngg * MBLK;               // 64 consecutive batch rows
    const int t    = t0 + tl;

    __shared__ __align__(16) short oh[MBLK][552];   // 70.6 KB
    __shared__ __align__(16) short xs[MBLK][264];   // 33.8 KB

    for (int i = tid; i < (MBLK * 552) / 8; i += 512)
        ((int4*)&oh[0][0])[i] = (int4){0, 0, 0, 0};
    __syncthreads();

    for (int i = tid; i < MBLK * NCODES; i += 512) {
        const int r = i / NCODES;
        const int j = i - r * NCODES;
        const int c = code[((size_t)(n0 + r) * T_STEPS + t) * NCODES + j];
        if (c > 0) ((unsigned short*)&oh[0][0])[r * 552 + (c - 1)] = 0x3F80;
    }
    for (int i = tid; i < MBLK * AUXD; i += 512) {
        const int r = i / AUXD;
        const int a = i - r * AUXD;
        oh[r][MH + a] = f2bf(aux[((size_t)(n0 + r) * T_STEPS + t) * AUXD + a]);
    }
    __syncthreads();

    const short* wfl_thr = WfL + (size_t)w * 512 + lane * 8;
    const short* wfk_thr = WfK + (size_t)w * 512 + lane * 8;

    // ---- Phase 2: xs = relu(oh @ WfL^T + b_lin), wave cols w*32.. ----
    {
        f32x4 acc[4][2];
        #pragma unroll
        for (int rb = 0; rb < 4; ++rb)
            #pragma unroll
            for (int cb = 0; cb < 2; ++cb)
                acc[rb][cb] = (f32x4){0.f, 0.f, 0.f, 0.f};

        for (int kk = 0; kk < 17; ++kk) {
            short8 a[4];
            #pragma unroll
            for (int rb = 0; rb < 4; ++rb)
                a[rb] = *(const short8*)&oh[rb * 16 + lr][kk * 32 + p * 8];
            #pragma unroll
            for (int cb = 0; cb < 2; ++cb) {
                short8 bf = *(const short8*)(wfl_thr + (size_t)(kk * 2 + cb) * 4096);
                #pragma unroll
                for (int rb = 0; rb < 4; ++rb)
                    acc[rb][cb] = __builtin_amdgcn_mfma_f32_16x16x32_bf16(
                        a[rb], bf, acc[rb][cb], 0, 0, 0);
            }
        }
        float bias[2];
        #pragma unroll
        for (int cb = 0; cb < 2; ++cb) bias[cb] = b_lin[w * 32 + cb * 16 + lr];
        #pragma unroll
        for (int rb = 0; rb < 4; ++rb)
            #pragma unroll
            for (int cb = 0; cb < 2; ++cb)
                #pragma unroll
                for (int rr = 0; rr < 4; ++rr)
                    xs[rb * 16 + p * 4 + rr][w * 32 + cb * 16 + lr] =
                        f2bf(fmaxf(acc[rb][cb][rr] + bias[cb], 0.f));
        __syncthreads();
    }

    // ---- Phase 3: xz = xs @ WfK^T, two cb-halves, R7-frag-order output ----
    #pragma unroll
    for (int half = 0; half < 2; ++half) {
        f32x4 acc[4][4];
        #pragma unroll
        for (int rb = 0; rb < 4; ++rb)
            #pragma unroll
            for (int c4 = 0; c4 < 4; ++c4)
                acc[rb][c4] = (f32x4){0.f, 0.f, 0.f, 0.f};

        for (int kb = 0; kb < 8; ++kb) {
            short8 a[4];
            #pragma unroll
            for (int rb = 0; rb < 4; ++rb)
                a[rb] = *(const short8*)&xs[rb * 16 + lr][kb * 32 + p * 8];
            #pragma unroll
            for (int c4 = 0; c4 < 4; ++c4) {
                const int cb = half * 4 + c4;
                short8 bf = *(const short8*)(wfk_thr + (size_t)(kb * 8 + cb) * 4096);
                #pragma unroll
                for (int rb = 0; rb < 4; ++rb)
                    acc[rb][c4] = __builtin_amdgcn_mfma_f32_16x16x32_bf16(
                        a[rb], bf, acc[rb][c4], 0, 0, 0);
            }
        }
        #pragma unroll
        for (int rb = 0; rb < 4; ++rb) {
            const int rgg = ngg * 4 + rb;   // global 16-row group
            #pragma unroll
            for (int c4 = 0; c4 < 4; ++c4) {
                const int cb = half * 4 + c4;
                const int c0 = w * 128 + cb * 16;
                const int g  = c0 >> 8;
                const int wp = (c0 >> 5) & 7;
                const int eb = (c0 >> 4) & 1;
                const int j8 = eb * 4 + g;
                short4v v;
                #pragma unroll
                for (int rr = 0; rr < 4; ++rr) v[rr] = f2bf(acc[rb][c4][rr]);
                *(short4v*)(xzp +
                    (((size_t)rgg * TCHUNK + tl) * 64 + wp * 8 + j8) * 256 +
                    lane * 4) = v;
            }
        }
    }
}

// ---------------------------------------------------------------------------
// Recurrence v7: R7 shape (128 blocks x 512 thr, 8 waves, BM=16) with
// (1) launch_bounds(512,2) -> 256 VGPR, window-4 rolling weight pipeline
//     (32 KB/wave in flight), (2) per-block kk-phase rotation to de-sync the
//     all-CUs-same-address L2 storm, (3) weights issued before xz prefetch.
// ---------------------------------------------------------------------------
__global__ __launch_bounds__(512, 2) void k_rec(
    const short* __restrict__ xzp, const int* __restrict__ length,
    const short* __restrict__ Wrec, const float* __restrict__ b,
    short* __restrict__ h_state, float* __restrict__ c_state,
    float* __restrict__ xlast, int t0)
{
    const int tid  = threadIdx.x;
    const int w    = tid >> 6;
    const int lane = tid & 63;
    const int lr   = lane & 15;
    const int p    = lane >> 4;
    const int rgg  = blockIdx.x;
    const int r0   = rgg * BM;

    __shared__ __align__(16) short h_f[2][8][512]; // [buf][kk][lane*8+j], 16KB
    __shared__ int s_len[BM];
    __shared__ int s_maxlen;

    if (tid < BM) s_len[tid] = length[r0 + tid];
    __syncthreads();
    if (tid == 0) {
        int m = 0;
        for (int r2 = 0; r2 < BM; ++r2) m = max(m, s_len[r2]);
        s_maxlen = m;
    }
    __syncthreads();
    const int mlen = s_maxlen;
    if (mlen <= t0) return;
    const int steps = min(TCHUNK, mlen - t0);

    int len_r[4];
    #pragma unroll
    for (int rr = 0; rr < 4; ++rr) len_r[rr] = s_len[p * 4 + rr];

    float bias[8];
    #pragma unroll
    for (int eb = 0; eb < 2; ++eb)
        #pragma unroll
        for (int g = 0; g < 4; ++g)
            bias[eb * 4 + g] = b[g * 256 + w * 32 + eb * 16 + lr];

    int hoff[2];
    #pragma unroll
    for (int eb = 0; eb < 2; ++eb)
        hoff[eb] = ((eb * 2 + (lr >> 3)) * 16) * 8 + (lr & 7);

    float creg[8];
    if (t0 == 0) {
        for (int i = tid; i < 4096; i += 512) ((int*)h_f)[i] = 0;
        #pragma unroll
        for (int i = 0; i < 8; ++i) creg[i] = 0.f;
    } else {
        #pragma unroll
        for (int eb = 0; eb < 2; ++eb)
            #pragma unroll
            for (int rr = 0; rr < 4; ++rr) {
                const int row = r0 + p * 4 + rr;
                const int e   = w * 32 + eb * 16 + lr;
                creg[eb * 4 + rr] = c_state[(size_t)row * E_DIM + e];
                h_f[0][w][hoff[eb] + (p * 4 + rr) * 8] =
                    h_state[(size_t)row * E_DIM + e];
            }
    }
    __syncthreads();

    const int ph = rgg & 7;                    // per-block phase rotation
    const short* wthr = Wrec + (size_t)w * 512 + lane * 8;
    const short* xzb  = xzp + ((size_t)rgg * TCHUNK) * 16384 +
                        (size_t)(w * 8) * 256 + lane * 4;

    // prefetch xz for tl=0
    short4v xv[8];
    #pragma unroll
    for (int j8 = 0; j8 < 8; ++j8)
        xv[j8] = *(const short4v*)(xzb + j8 * 256);

    int cur = 0;
    for (int tl = 0; tl < steps; ++tl) {
        const int t = t0 + tl;

        // acc init from prefetched xz
        f32x4 acc[8];
        #pragma unroll
        for (int j8 = 0; j8 < 8; ++j8)
            #pragma unroll
            for (int rr = 0; rr < 4; ++rr)
                acc[j8][rr] = bf2f((unsigned short)xv[j8][rr]);

        // weight pipeline prologue: window of 4 kk-groups, phase-rotated
        short8 bw[4][8];
        #pragma unroll
        for (int i = 0; i < 4; ++i) {
            const int kk = (ph + i) & 7;
            #pragma unroll
            for (int j8 = 0; j8 < 8; ++j8)
                bw[i][j8] = *(const short8*)(wthr + (size_t)(kk * 8 + j8) * 4096);
        }

        // xz prefetch for next step (after weights: in-order vmcnt friendly)
        if (tl + 1 < steps) {
            #pragma unroll
            for (int j8 = 0; j8 < 8; ++j8)
                xv[j8] = *(const short4v*)(xzb + (size_t)(tl + 1) * 16384 + j8 * 256);
        }

        // h @ R: 8 kk-groups, rolling refill 4 ahead
        #pragma unroll
        for (int i = 0; i < 8; ++i) {
            const int kk = (ph + i) & 7;
            short8 a = *(const short8*)&h_f[cur][kk][lane * 8];
            #pragma unroll
            for (int j8 = 0; j8 < 8; ++j8)
                acc[j8] = __builtin_amdgcn_mfma_f32_16x16x32_bf16(
                    a, bw[i & 3][j8], acc[j8], 0, 0, 0);
            if (i + 4 < 8) {
                const int kn = (ph + i + 4) & 7;
                #pragma unroll
                for (int j8 = 0; j8 < 8; ++j8)
                    bw[i & 3][j8] = *(const short8*)(wthr + (size_t)(kn * 8 + j8) * 4096);
            }
        }

        // gates in registers
        short* hw = &h_f[cur ^ 1][w][0];
        #pragma unroll
        for (int eb = 0; eb < 2; ++eb) {
            #pragma unroll
            for (int rr = 0; rr < 4; ++rr) {
                float zi = acc[eb * 4 + 0][rr] + bias[eb * 4 + 0];
                float zf = acc[eb * 4 + 1][rr] + bias[eb * 4 + 1];
                float zg = acc[eb * 4 + 2][rr] + bias[eb * 4 + 2];
                float zo = acc[eb * 4 + 3][rr] + bias[eb * 4 + 3];
                float ig = sigf(zi), fg = sigf(zf);
                float gg = tanhfast(zg), og = sigf(zo);
                float cc = fg * creg[eb * 4 + rr] + ig * gg;
                float hh = og * tanhfast(cc);
                creg[eb * 4 + rr] = cc;
                const short hb = f2bf(hh);
                hw[hoff[eb] + (p * 4 + rr) * 8] = hb;
                const int row = r0 + p * 4 + rr;
                const int e   = w * 32 + eb * 16 + lr;
                if (t == len_r[rr] - 1)
                    xlast[(size_t)row * E_DIM + e] = hh;
                if (tl == steps - 1) {
                    h_state[(size_t)row * E_DIM + e] = hb;
                    c_state[(size_t)row * E_DIM + e] = cc;
                }
            }
        }
        cur ^= 1;
        __syncthreads();   // new h visible before next step's a-reads
    }
}

// ---------------------------------------------------------------------------
// Head MLP + L2 normalize (unchanged).
// ---------------------------------------------------------------------------
__global__ __launch_bounds__(256) void k_head(
    const float* __restrict__ xlast,
    const float* __restrict__ W0, const float* __restrict__ b0,
    const float* __restrict__ W1, const float* __restrict__ b1,
    float* __restrict__ out)
{
    const int n = blockIdx.x;
    const int j = threadIdx.x;

    __shared__ __align__(16) float xsh[E_DIM];
    __shared__ __align__(16) float y0[E_DIM];
    __shared__ float part[4];

    xsh[j] = xlast[(size_t)n * E_DIM + j];
    __syncthreads();

    float acc = b0[j];
    for (int k4 = 0; k4 < E_DIM; k4 += 4) {
        float4 xv = *reinterpret_cast<const float4*>(&xsh[k4]);
        #pragma unroll
        for (int kk = 0; kk < 4; ++kk)
            acc += (&xv.x)[kk] * W0[(size_t)(k4 + kk) * E_DIM + j];
    }
    y0[j] = fmaxf(acc, 0.f);
    __syncthreads();

    acc = b1[j];
    for (int k4 = 0; k4 < E_DIM; k4 += 4) {
        float4 yv = *reinterpret_cast<const float4*>(&y0[k4]);
        #pragma unroll
        for (int kk = 0; kk < 4; ++kk)
            acc += (&yv.x)[kk] * W1[(size_t)(k4 + kk) * E_DIM + j];
    }

    float sq = acc * acc;
    #pragma unroll
    for (int off = 32; off > 0; off >>= 1)
        sq += __shfl_xor(sq, off, 64);
    if ((j & 63) == 0) part[j >> 6] = sq;
    __syncthreads();
    float total = part[0] + part[1] + part[2] + part[3];

    out[(size_t)n * E_DIM + j] = acc * rsqrtf(total);
}

// ---------------------------------------------------------------------------
extern "C" void kernel_launch(void* const* d_in, const int* in_sizes, int n_in,
                              void* d_out, int out_size, void* d_ws, size_t ws_size,
                              hipStream_t stream) {
    const int*   code   = (const int*)  d_in[0];
    const float* aux    = (const float*)d_in[1];
    const int*   length = (const int*)  d_in[2];
    // d_in[3] = is_training (ignored)
    const float* W_lin  = (const float*)d_in[4];
    const float* b_lin  = (const float*)d_in[5];
    const float* K      = (const float*)d_in[6];
    const float* R      = (const float*)d_in[7];
    const float* b      = (const float*)d_in[8];
    const float* W0     = (const float*)d_in[9];
    const float* b0     = (const float*)d_in[10];
    const float* W1     = (const float*)d_in[11];
    const float* b1     = (const float*)d_in[12];
    float* out = (float*)d_out;

    // workspace layout (bytes, 16B aligned); total ~48.5 MB
    char* ws = (char*)d_ws;
    short* Wrec    = (short*)(ws + 0);            //    524,288
    short* WfK     = (short*)(ws + 524288);       //    524,288
    short* WfL     = (short*)(ws + 1048576);      //    278,528
    float* xlast   = (float*)(ws + 1327104);      //  2,097,152
    short* h_state = (short*)(ws + 3424256);      //  1,048,576
    float* c_state = (float*)(ws + 4472832);      //  2,097,152
    short* xzp     = (short*)(ws + 6569984);      // 41,943,040

    k_prep_wrec<<<128, 256, 0, stream>>>(R, Wrec);
    k_prep_wfk <<<128, 256, 0, stream>>>(K, WfK);
    k_prep_wfl <<<68,  256, 0, stream>>>(W_lin, WfL);

    for (int c = 0; c < T_STEPS / TCHUNK; ++c) {
        const int t0 = c * TCHUNK;
        k_fused<<<TCHUNK * 32, 512, 0, stream>>>(
            code, aux, WfL, b_lin, WfK, xzp, t0);
        k_rec<<<N_BATCH / BM, 512, 0, stream>>>(xzp, length, Wrec, b,
                                                h_state, c_state, xlast, t0);
    }

    k_head<<<N_BATCH, 256, 0, stream>>>(xlast, W0, b0, W1, b1, out);
}

// Round 11
// 808.553 us; speedup vs baseline: 1.0433x; 1.0433x over previous
//
#include <hip/hip_runtime.h>
#include <hip/hip_bf16.h>
#include <math.h>

#define N_BATCH 2048
#define T_STEPS 50
#define NCODES  40
#define MH      526
#define AUXD    10
#define WLROWS  536    // MH + AUXD
#define E_DIM   256
#define G_DIM   1024   // 4*E
#define BM      16     // batch rows per recurrence block
#define TCHUNK  10     // time steps per chunk (5 chunks)
#define MBLK    64     // (n,t) rows per fused block
#define NFUSED  (TCHUNK * 32)   // 320 fused blocks per chunk
#define XZSZ    (N_BATCH * TCHUNK * G_DIM)   // shorts per xz parity buffer

typedef __attribute__((ext_vector_type(8))) short short8;   // 8 bf16 = 4 VGPR
typedef __attribute__((ext_vector_type(4))) short short4v;  // 4 bf16 = 2 VGPR
typedef __attribute__((ext_vector_type(4))) float f32x4;

__device__ __forceinline__ short f2bf(float f) {
    __hip_bfloat16 h = __float2bfloat16(f);
    return *reinterpret_cast<short*>(&h);
}
__device__ __forceinline__ float bf2f(unsigned short u) {
    return __uint_as_float(((unsigned int)u) << 16);
}
__device__ __forceinline__ float sigf(float x) {
    return 1.f / (1.f + __expf(-x));
}
__device__ __forceinline__ float tanhfast(float x) {
    return 2.f / (1.f + __expf(-2.f * x)) - 1.f;
}

// ---------------------------------------------------------------------------
// Wrec (R for rec), R7 layout: fg = (kk*8 + j8)*8 + w ; j8 = eb*4 + g
//   Wrec[fg*512 + lane*8 + j] = R[kk*32 + p*8 + j][g*256 + w*32 + eb*16 + lr]
// ---------------------------------------------------------------------------
__global__ __launch_bounds__(256) void k_prep_wrec(
    const float* __restrict__ R, short* __restrict__ Wrec)
{
    const int gid  = blockIdx.x * 256 + threadIdx.x;   // 32768
    const int fg   = gid >> 6, lane = gid & 63;
    const int p    = lane >> 4, lr = lane & 15;
    const int kk   = fg >> 6;
    const int j8   = (fg >> 3) & 7;
    const int w    = fg & 7;
    const int eb   = j8 >> 2, g = j8 & 3;
    const int n    = g * 256 + w * 32 + eb * 16 + lr;
    short* dst = Wrec + (size_t)fg * 512 + lane * 8;
    #pragma unroll
    for (int j = 0; j < 8; ++j)
        dst[j] = f2bf(R[(size_t)(kk * 32 + p * 8 + j) * G_DIM + n]);
}

// WfK (K for fused phase 3): fg = (kb*8 + cb)*8 + w
__global__ __launch_bounds__(256) void k_prep_wfk(
    const float* __restrict__ K, short* __restrict__ WfK)
{
    const int gid  = blockIdx.x * 256 + threadIdx.x;   // 32768
    const int fg   = gid >> 6, lane = gid & 63;
    const int p    = lane >> 4, lr = lane & 15;
    const int kb   = fg >> 6;
    const int cb   = (fg >> 3) & 7;
    const int w    = fg & 7;
    const int n    = w * 128 + cb * 16 + lr;
    short* dst = WfK + (size_t)fg * 512 + lane * 8;
    #pragma unroll
    for (int j = 0; j < 8; ++j)
        dst[j] = f2bf(K[(size_t)(kb * 32 + p * 8 + j) * G_DIM + n]);
}

// WfL (W_lin for fused phase 2): fg = (kk*2 + cb)*8 + w, kk 0..16
__global__ __launch_bounds__(256) void k_prep_wfl(
    const float* __restrict__ W_lin, short* __restrict__ WfL)
{
    const int gid  = blockIdx.x * 256 + threadIdx.x;   // 17408
    const int fg   = gid >> 6, lane = gid & 63;
    const int p    = lane >> 4, lr = lane & 15;
    const int kk   = fg >> 4;
    const int cb   = (fg >> 3) & 1;
    const int w    = fg & 7;
    const int n    = w * 32 + cb * 16 + lr;
    short* dst = WfL + (size_t)fg * 512 + lane * 8;
    #pragma unroll
    for (int j = 0; j < 8; ++j) {
        const int k = kk * 32 + p * 8 + j;
        dst[j] = (k < WLROWS) ? f2bf(W_lin[(size_t)k * E_DIM + n]) : (short)0;
    }
}

// ---------------------------------------------------------------------------
// Fused-role device body: embed + xz GEMM for one (tl, 64-row) tile.
// Writes xz_w in rec fragment order:
//   idx = ((rgg*TCHUNK + tl)*64 + wp*8 + j8)*256 + lane*4
// Phase-rotated weight sweeps: ph = (fid>>3) decorrelates same-XCD blocks.
// ---------------------------------------------------------------------------
__device__ __forceinline__ void fused_body(
    int fid, short* smem,
    const int* __restrict__ code, const float* __restrict__ aux,
    const short* __restrict__ WfL, const float* __restrict__ b_lin,
    const short* __restrict__ WfK, short* __restrict__ xz_w, int t0f)
{
    const int tid  = threadIdx.x;
    const int w    = tid >> 6;
    const int lane = tid & 63;
    const int lr   = lane & 15;
    const int p    = lane >> 4;
    const int tl   = fid >> 5;                 // 0..TCHUNK-1
    const int ngg  = fid & 31;
    const int n0   = ngg * MBLK;               // 64 consecutive batch rows
    const int t    = t0f + tl;
    const int ph8  = (fid >> 3) & 7;
    const int ph17 = (fid >> 3) % 17;

    short (*oh)[552] = (short (*)[552])smem;               // 70656 B
    short (*xs)[264] = (short (*)[264])(smem + MBLK * 552);// 33792 B

    for (int i = tid; i < (MBLK * 552) / 8; i += 512)
        ((int4*)&oh[0][0])[i] = (int4){0, 0, 0, 0};
    __syncthreads();

    for (int i = tid; i < MBLK * NCODES; i += 512) {
        const int r = i / NCODES;
        const int j = i - r * NCODES;
        const int c = code[((size_t)(n0 + r) * T_STEPS + t) * NCODES + j];
        if (c > 0) ((unsigned short*)&oh[0][0])[r * 552 + (c - 1)] = 0x3F80;
    }
    for (int i = tid; i < MBLK * AUXD; i += 512) {
        const int r = i / AUXD;
        const int a = i - r * AUXD;
        oh[r][MH + a] = f2bf(aux[((size_t)(n0 + r) * T_STEPS + t) * AUXD + a]);
    }
    __syncthreads();

    const short* wfl_thr = WfL + (size_t)w * 512 + lane * 8;
    const short* wfk_thr = WfK + (size_t)w * 512 + lane * 8;

    // ---- Phase 2: xs = relu(oh @ WfL^T + b_lin), wave cols w*32.. ----
    {
        f32x4 acc[4][2];
        #pragma unroll
        for (int rb = 0; rb < 4; ++rb)
            #pragma unroll
            for (int cb = 0; cb < 2; ++cb)
                acc[rb][cb] = (f32x4){0.f, 0.f, 0.f, 0.f};

        for (int kk = 0; kk < 17; ++kk) {
            int kx = kk + ph17; if (kx >= 17) kx -= 17;   // rotated sweep
            short8 a[4];
            #pragma unroll
            for (int rb = 0; rb < 4; ++rb)
                a[rb] = *(const short8*)&oh[rb * 16 + lr][kx * 32 + p * 8];
            #pragma unroll
            for (int cb = 0; cb < 2; ++cb) {
                short8 bf = *(const short8*)(wfl_thr + (size_t)(kx * 2 + cb) * 4096);
                #pragma unroll
                for (int rb = 0; rb < 4; ++rb)
                    acc[rb][cb] = __builtin_amdgcn_mfma_f32_16x16x32_bf16(
                        a[rb], bf, acc[rb][cb], 0, 0, 0);
            }
        }
        float bias[2];
        #pragma unroll
        for (int cb = 0; cb < 2; ++cb) bias[cb] = b_lin[w * 32 + cb * 16 + lr];
        #pragma unroll
        for (int rb = 0; rb < 4; ++rb)
            #pragma unroll
            for (int cb = 0; cb < 2; ++cb)
                #pragma unroll
                for (int rr = 0; rr < 4; ++rr)
                    xs[rb * 16 + p * 4 + rr][w * 32 + cb * 16 + lr] =
                        f2bf(fmaxf(acc[rb][cb][rr] + bias[cb], 0.f));
        __syncthreads();
    }

    // ---- Phase 3: xz = xs @ WfK^T, two cb-halves, frag-order output ----
    #pragma unroll
    for (int half = 0; half < 2; ++half) {
        f32x4 acc[4][4];
        #pragma unroll
        for (int rb = 0; rb < 4; ++rb)
            #pragma unroll
            for (int c4 = 0; c4 < 4; ++c4)
                acc[rb][c4] = (f32x4){0.f, 0.f, 0.f, 0.f};

        for (int kb = 0; kb < 8; ++kb) {
            const int kx = (kb + ph8) & 7;                // rotated sweep
            short8 a[4];
            #pragma unroll
            for (int rb = 0; rb < 4; ++rb)
                a[rb] = *(const short8*)&xs[rb * 16 + lr][kx * 32 + p * 8];
            #pragma unroll
            for (int c4 = 0; c4 < 4; ++c4) {
                const int cb = half * 4 + c4;
                short8 bf = *(const short8*)(wfk_thr + (size_t)(kx * 8 + cb) * 4096);
                #pragma unroll
                for (int rb = 0; rb < 4; ++rb)
                    acc[rb][c4] = __builtin_amdgcn_mfma_f32_16x16x32_bf16(
                        a[rb], bf, acc[rb][c4], 0, 0, 0);
            }
        }
        #pragma unroll
        for (int rb = 0; rb < 4; ++rb) {
            const int rgg = ngg * 4 + rb;   // global 16-row group
            #pragma unroll
            for (int c4 = 0; c4 < 4; ++c4) {
                const int cb = half * 4 + c4;
                const int c0 = w * 128 + cb * 16;
                const int g  = c0 >> 8;
                const int wp = (c0 >> 5) & 7;
                const int eb = (c0 >> 4) & 1;
                const int j8 = eb * 4 + g;
                short4v v;
                #pragma unroll
                for (int rr = 0; rr < 4; ++rr) v[rr] = f2bf(acc[rb][c4][rr]);
                *(short4v*)(xz_w +
                    (((size_t)rgg * TCHUNK + tl) * 64 + wp * 8 + j8) * 256 +
                    lane * 4) = v;
            }
        }
    }
}

// ---------------------------------------------------------------------------
// Rec-role device body: 10 LSTM steps for 16 rows; weights streamed from
// Wrec with window-4 pipeline; kk-sweep phase = (rgg>>3)&7 so the 16
// same-XCD blocks (rgg ≡ const mod 8) start at 8 distinct 64-KB offsets.
// ---------------------------------------------------------------------------
__device__ __forceinline__ void rec_body(
    int rgg, short* smem,
    const short* __restrict__ xz_r, const int* __restrict__ length,
    const short* __restrict__ Wrec, const float* __restrict__ b,
    short* __restrict__ h_state, float* __restrict__ c_state,
    float* __restrict__ xlast, int t0)
{
    const int tid  = threadIdx.x;
    const int w    = tid >> 6;
    const int lane = tid & 63;
    const int lr   = lane & 15;
    const int p    = lane >> 4;
    const int r0   = rgg * BM;

    short (*h_f)[8][512] = (short (*)[8][512])smem;   // [2][8][512], 16 KB
    __shared__ int s_len[BM];
    __shared__ int s_maxlen;

    if (tid < BM) s_len[tid] = length[r0 + tid];
    __syncthreads();
    if (tid == 0) {
        int m = 0;
        for (int r2 = 0; r2 < BM; ++r2) m = max(m, s_len[r2]);
        s_maxlen = m;
    }
    __syncthreads();
    const int mlen = s_maxlen;
    if (mlen <= t0) return;
    const int steps = min(TCHUNK, mlen - t0);

    int len_r[4];
    #pragma unroll
    for (int rr = 0; rr < 4; ++rr) len_r[rr] = s_len[p * 4 + rr];

    float bias[8];
    #pragma unroll
    for (int eb = 0; eb < 2; ++eb)
        #pragma unroll
        for (int g = 0; g < 4; ++g)
            bias[eb * 4 + g] = b[g * 256 + w * 32 + eb * 16 + lr];

    int hoff[2];
    #pragma unroll
    for (int eb = 0; eb < 2; ++eb)
        hoff[eb] = ((eb * 2 + (lr >> 3)) * 16) * 8 + (lr & 7);

    float creg[8];
    if (t0 == 0) {
        for (int i = tid; i < 4096; i += 512) ((int*)h_f)[i] = 0;
        #pragma unroll
        for (int i = 0; i < 8; ++i) creg[i] = 0.f;
    } else {
        #pragma unroll
        for (int eb = 0; eb < 2; ++eb)
            #pragma unroll
            for (int rr = 0; rr < 4; ++rr) {
                const int row = r0 + p * 4 + rr;
                const int e   = w * 32 + eb * 16 + lr;
                creg[eb * 4 + rr] = c_state[(size_t)row * E_DIM + e];
                h_f[0][w][hoff[eb] + (p * 4 + rr) * 8] =
                    h_state[(size_t)row * E_DIM + e];
            }
    }
    __syncthreads();

    const int ph = (rgg >> 3) & 7;             // per-XCD-decorrelated phase
    const short* wthr = Wrec + (size_t)w * 512 + lane * 8;
    const short* xzb  = xz_r + ((size_t)rgg * TCHUNK) * 16384 +
                        (size_t)(w * 8) * 256 + lane * 4;

    // prefetch xz for tl=0
    short4v xv[8];
    #pragma unroll
    for (int j8 = 0; j8 < 8; ++j8)
        xv[j8] = *(const short4v*)(xzb + j8 * 256);

    int cur = 0;
    for (int tl = 0; tl < steps; ++tl) {
        const int t = t0 + tl;

        f32x4 acc[8];
        #pragma unroll
        for (int j8 = 0; j8 < 8; ++j8)
            #pragma unroll
            for (int rr = 0; rr < 4; ++rr)
                acc[j8][rr] = bf2f((unsigned short)xv[j8][rr]);

        // weight pipeline prologue: window of 4 kk-groups, phase-rotated
        short8 bw[4][8];
        #pragma unroll
        for (int i = 0; i < 4; ++i) {
            const int kk = (ph + i) & 7;
            #pragma unroll
            for (int j8 = 0; j8 < 8; ++j8)
                bw[i][j8] = *(const short8*)(wthr + (size_t)(kk * 8 + j8) * 4096);
        }

        if (tl + 1 < steps) {
            #pragma unroll
            for (int j8 = 0; j8 < 8; ++j8)
                xv[j8] = *(const short4v*)(xzb + (size_t)(tl + 1) * 16384 + j8 * 256);
        }

        // h @ R: 8 kk-groups, rolling refill 4 ahead (kk runtime only in addr)
        #pragma unroll
        for (int i = 0; i < 8; ++i) {
            const int kk = (ph + i) & 7;
            short8 a = *(const short8*)&h_f[cur][kk][lane * 8];
            #pragma unroll
            for (int j8 = 0; j8 < 8; ++j8)
                acc[j8] = __builtin_amdgcn_mfma_f32_16x16x32_bf16(
                    a, bw[i & 3][j8], acc[j8], 0, 0, 0);
            if (i + 4 < 8) {
                const int kn = (ph + i + 4) & 7;
                #pragma unroll
                for (int j8 = 0; j8 < 8; ++j8)
                    bw[i & 3][j8] = *(const short8*)(wthr + (size_t)(kn * 8 + j8) * 4096);
            }
        }

        // gates in registers
        short* hw = &h_f[cur ^ 1][w][0];
        #pragma unroll
        for (int eb = 0; eb < 2; ++eb) {
            #pragma unroll
            for (int rr = 0; rr < 4; ++rr) {
                float zi = acc[eb * 4 + 0][rr] + bias[eb * 4 + 0];
                float zf = acc[eb * 4 + 1][rr] + bias[eb * 4 + 1];
                float zg = acc[eb * 4 + 2][rr] + bias[eb * 4 + 2];
                float zo = acc[eb * 4 + 3][rr] + bias[eb * 4 + 3];
                float ig = sigf(zi), fg = sigf(zf);
                float gg = tanhfast(zg), og = sigf(zo);
                float cc = fg * creg[eb * 4 + rr] + ig * gg;
                float hh = og * tanhfast(cc);
                creg[eb * 4 + rr] = cc;
                const short hb = f2bf(hh);
                hw[hoff[eb] + (p * 4 + rr) * 8] = hb;
                const int row = r0 + p * 4 + rr;
                const int e   = w * 32 + eb * 16 + lr;
                if (t == len_r[rr] - 1)
                    xlast[(size_t)row * E_DIM + e] = hh;
                if (tl == steps - 1) {
                    h_state[(size_t)row * E_DIM + e] = hb;
                    c_state[(size_t)row * E_DIM + e] = cc;
                }
            }
        }
        cur ^= 1;
        __syncthreads();
    }
}

// ---------------------------------------------------------------------------
// Combo: blocks [0, rec_cnt) run rec(chunk c); blocks [rec_cnt, ..) run
// fused(chunk c+1). Independent work -> fused hides under rec's stalls.
// ---------------------------------------------------------------------------
__global__ __launch_bounds__(512, 1) void k_combo(
    const int* __restrict__ code, const float* __restrict__ aux,
    const short* __restrict__ WfL, const float* __restrict__ b_lin,
    const short* __restrict__ WfK,
    const short* __restrict__ Wrec, const float* __restrict__ b,
    const int* __restrict__ length,
    short* __restrict__ h_state, float* __restrict__ c_state,
    float* __restrict__ xlast,
    const short* __restrict__ xz_r, short* __restrict__ xz_w,
    int t0r, int t0f, int rec_cnt)
{
    __shared__ __align__(16) short smem[52224];   // 104448 B shared arena
    const int bid = blockIdx.x;
    if (bid < rec_cnt) {
        rec_body(bid, smem, xz_r, length, Wrec, b,
                 h_state, c_state, xlast, t0r);
    } else if (t0f >= 0) {
        fused_body(bid - rec_cnt, smem, code, aux, WfL, b_lin, WfK,
                   xz_w, t0f);
    }
}

// ---------------------------------------------------------------------------
// Head MLP + L2 normalize (unchanged).
// ---------------------------------------------------------------------------
__global__ __launch_bounds__(256) void k_head(
    const float* __restrict__ xlast,
    const float* __restrict__ W0, const float* __restrict__ b0,
    const float* __restrict__ W1, const float* __restrict__ b1,
    float* __restrict__ out)
{
    const int n = blockIdx.x;
    const int j = threadIdx.x;

    __shared__ __align__(16) float xsh[E_DIM];
    __shared__ __align__(16) float y0[E_DIM];
    __shared__ float part[4];

    xsh[j] = xlast[(size_t)n * E_DIM + j];
    __syncthreads();

    float acc = b0[j];
    for (int k4 = 0; k4 < E_DIM; k4 += 4) {
        float4 xv = *reinterpret_cast<const float4*>(&xsh[k4]);
        #pragma unroll
        for (int kk = 0; kk < 4; ++kk)
            acc += (&xv.x)[kk] * W0[(size_t)(k4 + kk) * E_DIM + j];
    }
    y0[j] = fmaxf(acc, 0.f);
    __syncthreads();

    acc = b1[j];
    for (int k4 = 0; k4 < E_DIM; k4 += 4) {
        float4 yv = *reinterpret_cast<const float4*>(&y0[k4]);
        #pragma unroll
        for (int kk = 0; kk < 4; ++kk)
            acc += (&yv.x)[kk] * W1[(size_t)(k4 + kk) * E_DIM + j];
    }

    float sq = acc * acc;
    #pragma unroll
    for (int off = 32; off > 0; off >>= 1)
        sq += __shfl_xor(sq, off, 64);
    if ((j & 63) == 0) part[j >> 6] = sq;
    __syncthreads();
    float total = part[0] + part[1] + part[2] + part[3];

    out[(size_t)n * E_DIM + j] = acc * rsqrtf(total);
}

// ---------------------------------------------------------------------------
extern "C" void kernel_launch(void* const* d_in, const int* in_sizes, int n_in,
                              void* d_out, int out_size, void* d_ws, size_t ws_size,
                              hipStream_t stream) {
    const int*   code   = (const int*)  d_in[0];
    const float* aux    = (const float*)d_in[1];
    const int*   length = (const int*)  d_in[2];
    // d_in[3] = is_training (ignored)
    const float* W_lin  = (const float*)d_in[4];
    const float* b_lin  = (const float*)d_in[5];
    const float* K      = (const float*)d_in[6];
    const float* R      = (const float*)d_in[7];
    const float* b      = (const float*)d_in[8];
    const float* W0     = (const float*)d_in[9];
    const float* b0     = (const float*)d_in[10];
    const float* W1     = (const float*)d_in[11];
    const float* b1     = (const float*)d_in[12];
    float* out = (float*)d_out;

    // workspace layout (bytes, 16B aligned); total ~90.5 MB
    char* ws = (char*)d_ws;
    short* Wrec    = (short*)(ws + 0);            //    524,288
    short* WfK     = (short*)(ws + 524288);       //    524,288
    short* WfL     = (short*)(ws + 1048576);      //    278,528
    float* xlast   = (float*)(ws + 1327104);      //  2,097,152
    short* h_state = (short*)(ws + 3424256);      //  1,048,576
    float* c_state = (float*)(ws + 4472832);      //  2,097,152
    short* xzp0    = (short*)(ws + 6569984);      // 41,943,040
    short* xzp1    = (short*)(ws + 48513024);     // 41,943,040

    k_prep_wrec<<<128, 256, 0, stream>>>(R, Wrec);
    k_prep_wfk <<<128, 256, 0, stream>>>(K, WfK);
    k_prep_wfl <<<68,  256, 0, stream>>>(W_lin, WfL);

    short* xzbuf[2] = {xzp0, xzp1};

    // d1: fused-only for chunk 0 -> xzp0
    k_combo<<<NFUSED, 512, 0, stream>>>(
        code, aux, WfL, b_lin, WfK, Wrec, b, length,
        h_state, c_state, xlast, xzp0, xzp0, 0, 0, 0);

    // d2..d5: rec(chunk c) + fused(chunk c+1)
    for (int c = 0; c < 4; ++c) {
        k_combo<<<128 + NFUSED, 512, 0, stream>>>(
            code, aux, WfL, b_lin, WfK, Wrec, b, length,
            h_state, c_state, xlast,
            xzbuf[c & 1], xzbuf[(c + 1) & 1],
            c * TCHUNK, (c + 1) * TCHUNK, 128);
    }
    // d6: rec-only for chunk 4
    k_combo<<<128, 512, 0, stream>>>(
        code, aux, WfL, b_lin, WfK, Wrec, b, length,
        h_state, c_state, xlast, xzbuf[0], xzbuf[0],
        4 * TCHUNK, -1, 128);

    k_head<<<N_BATCH, 256, 0, stream>>>(xlast, W0, b0, W1, b1, out);
}

// Round 12
// 763.953 us; speedup vs baseline: 1.1042x; 1.0584x over previous
//
#include <hip/hip_runtime.h>
#include <hip/hip_bf16.h>
#include <math.h>

#define N_BATCH 2048
#define T_STEPS 50
#define NCODES  40
#define MH      526
#define AUXD    10
#define WLROWS  536    // MH + AUXD
#define E_DIM   256
#define G_DIM   1024   // 4*E
#define BM      16     // batch rows per recurrence block
#define TCHUNK  10     // time steps per chunk (5 chunks)
#define MBLK    64     // (n,t) rows per fused block
#define NFUSED  (TCHUNK * 32)   // 320 fused blocks per chunk

typedef __attribute__((ext_vector_type(8))) short short8;   // 8 bf16 = 4 VGPR
typedef __attribute__((ext_vector_type(4))) short short4v;  // 4 bf16 = 2 VGPR
typedef __attribute__((ext_vector_type(4))) float f32x4;

__device__ __forceinline__ short f2bf(float f) {
    __hip_bfloat16 h = __float2bfloat16(f);
    return *reinterpret_cast<short*>(&h);
}
__device__ __forceinline__ float bf2f(unsigned short u) {
    return __uint_as_float(((unsigned int)u) << 16);
}
__device__ __forceinline__ float sigf(float x) {
    return 1.f / (1.f + __expf(-x));
}
__device__ __forceinline__ float tanhfast(float x) {
    return 2.f / (1.f + __expf(-2.f * x)) - 1.f;
}

// ---------------------------------------------------------------------------
// Wrec (R for rec), R7 layout: fg = (kk*8 + j8)*8 + w ; j8 = eb*4 + g
//   Wrec[fg*512 + lane*8 + j] = R[kk*32 + p*8 + j][g*256 + w*32 + eb*16 + lr]
// ---------------------------------------------------------------------------
__global__ __launch_bounds__(256) void k_prep_wrec(
    const float* __restrict__ R, short* __restrict__ Wrec)
{
    const int gid  = blockIdx.x * 256 + threadIdx.x;   // 32768
    const int fg   = gid >> 6, lane = gid & 63;
    const int p    = lane >> 4, lr = lane & 15;
    const int kk   = fg >> 6;
    const int j8   = (fg >> 3) & 7;
    const int w    = fg & 7;
    const int eb   = j8 >> 2, g = j8 & 3;
    const int n    = g * 256 + w * 32 + eb * 16 + lr;
    short* dst = Wrec + (size_t)fg * 512 + lane * 8;
    #pragma unroll
    for (int j = 0; j < 8; ++j)
        dst[j] = f2bf(R[(size_t)(kk * 32 + p * 8 + j) * G_DIM + n]);
}

// WfK (K for fused phase 3): fg = (kb*8 + cb)*8 + w
__global__ __launch_bounds__(256) void k_prep_wfk(
    const float* __restrict__ K, short* __restrict__ WfK)
{
    const int gid  = blockIdx.x * 256 + threadIdx.x;   // 32768
    const int fg   = gid >> 6, lane = gid & 63;
    const int p    = lane >> 4, lr = lane & 15;
    const int kb   = fg >> 6;
    const int cb   = (fg >> 3) & 7;
    const int w    = fg & 7;
    const int n    = w * 128 + cb * 16 + lr;
    short* dst = WfK + (size_t)fg * 512 + lane * 8;
    #pragma unroll
    for (int j = 0; j < 8; ++j)
        dst[j] = f2bf(K[(size_t)(kb * 32 + p * 8 + j) * G_DIM + n]);
}

// WfL (W_lin for fused phase 2): fg = (kk*2 + cb)*8 + w, kk 0..16
__global__ __launch_bounds__(256) void k_prep_wfl(
    const float* __restrict__ W_lin, short* __restrict__ WfL)
{
    const int gid  = blockIdx.x * 256 + threadIdx.x;   // 17408
    const int fg   = gid >> 6, lane = gid & 63;
    const int p    = lane >> 4, lr = lane & 15;
    const int kk   = fg >> 4;
    const int cb   = (fg >> 3) & 1;
    const int w    = fg & 7;
    const int n    = w * 32 + cb * 16 + lr;
    short* dst = WfL + (size_t)fg * 512 + lane * 8;
    #pragma unroll
    for (int j = 0; j < 8; ++j) {
        const int k = kk * 32 + p * 8 + j;
        dst[j] = (k < WLROWS) ? f2bf(W_lin[(size_t)k * E_DIM + n]) : (short)0;
    }
}

// ---------------------------------------------------------------------------
// Fused-role device body (unchanged from R11).
// ---------------------------------------------------------------------------
__device__ __forceinline__ void fused_body(
    int fid, short* smem,
    const int* __restrict__ code, const float* __restrict__ aux,
    const short* __restrict__ WfL, const float* __restrict__ b_lin,
    const short* __restrict__ WfK, short* __restrict__ xz_w, int t0f)
{
    const int tid  = threadIdx.x;
    const int w    = tid >> 6;
    const int lane = tid & 63;
    const int lr   = lane & 15;
    const int p    = lane >> 4;
    const int tl   = fid >> 5;                 // 0..TCHUNK-1
    const int ngg  = fid & 31;
    const int n0   = ngg * MBLK;               // 64 consecutive batch rows
    const int t    = t0f + tl;
    const int ph8  = (fid >> 3) & 7;
    const int ph17 = (fid >> 3) % 17;

    short (*oh)[552] = (short (*)[552])smem;               // 70656 B
    short (*xs)[264] = (short (*)[264])(smem + MBLK * 552);// 33792 B

    for (int i = tid; i < (MBLK * 552) / 8; i += 512)
        ((int4*)&oh[0][0])[i] = (int4){0, 0, 0, 0};
    __syncthreads();

    for (int i = tid; i < MBLK * NCODES; i += 512) {
        const int r = i / NCODES;
        const int j = i - r * NCODES;
        const int c = code[((size_t)(n0 + r) * T_STEPS + t) * NCODES + j];
        if (c > 0) ((unsigned short*)&oh[0][0])[r * 552 + (c - 1)] = 0x3F80;
    }
    for (int i = tid; i < MBLK * AUXD; i += 512) {
        const int r = i / AUXD;
        const int a = i - r * AUXD;
        oh[r][MH + a] = f2bf(aux[((size_t)(n0 + r) * T_STEPS + t) * AUXD + a]);
    }
    __syncthreads();

    const short* wfl_thr = WfL + (size_t)w * 512 + lane * 8;
    const short* wfk_thr = WfK + (size_t)w * 512 + lane * 8;

    // ---- Phase 2: xs = relu(oh @ WfL^T + b_lin), wave cols w*32.. ----
    {
        f32x4 acc[4][2];
        #pragma unroll
        for (int rb = 0; rb < 4; ++rb)
            #pragma unroll
            for (int cb = 0; cb < 2; ++cb)
                acc[rb][cb] = (f32x4){0.f, 0.f, 0.f, 0.f};

        for (int kk = 0; kk < 17; ++kk) {
            int kx = kk + ph17; if (kx >= 17) kx -= 17;   // rotated sweep
            short8 a[4];
            #pragma unroll
            for (int rb = 0; rb < 4; ++rb)
                a[rb] = *(const short8*)&oh[rb * 16 + lr][kx * 32 + p * 8];
            #pragma unroll
            for (int cb = 0; cb < 2; ++cb) {
                short8 bf = *(const short8*)(wfl_thr + (size_t)(kx * 2 + cb) * 4096);
                #pragma unroll
                for (int rb = 0; rb < 4; ++rb)
                    acc[rb][cb] = __builtin_amdgcn_mfma_f32_16x16x32_bf16(
                        a[rb], bf, acc[rb][cb], 0, 0, 0);
            }
        }
        float bias[2];
        #pragma unroll
        for (int cb = 0; cb < 2; ++cb) bias[cb] = b_lin[w * 32 + cb * 16 + lr];
        #pragma unroll
        for (int rb = 0; rb < 4; ++rb)
            #pragma unroll
            for (int cb = 0; cb < 2; ++cb)
                #pragma unroll
                for (int rr = 0; rr < 4; ++rr)
                    xs[rb * 16 + p * 4 + rr][w * 32 + cb * 16 + lr] =
                        f2bf(fmaxf(acc[rb][cb][rr] + bias[cb], 0.f));
        __syncthreads();
    }

    // ---- Phase 3: xz = xs @ WfK^T, two cb-halves, frag-order output ----
    #pragma unroll
    for (int half = 0; half < 2; ++half) {
        f32x4 acc[4][4];
        #pragma unroll
        for (int rb = 0; rb < 4; ++rb)
            #pragma unroll
            for (int c4 = 0; c4 < 4; ++c4)
                acc[rb][c4] = (f32x4){0.f, 0.f, 0.f, 0.f};

        for (int kb = 0; kb < 8; ++kb) {
            const int kx = (kb + ph8) & 7;                // rotated sweep
            short8 a[4];
            #pragma unroll
            for (int rb = 0; rb < 4; ++rb)
                a[rb] = *(const short8*)&xs[rb * 16 + lr][kx * 32 + p * 8];
            #pragma unroll
            for (int c4 = 0; c4 < 4; ++c4) {
                const int cb = half * 4 + c4;
                short8 bf = *(const short8*)(wfk_thr + (size_t)(kx * 8 + cb) * 4096);
                #pragma unroll
                for (int rb = 0; rb < 4; ++rb)
                    acc[rb][c4] = __builtin_amdgcn_mfma_f32_16x16x32_bf16(
                        a[rb], bf, acc[rb][c4], 0, 0, 0);
            }
        }
        #pragma unroll
        for (int rb = 0; rb < 4; ++rb) {
            const int rgg = ngg * 4 + rb;   // global 16-row group
            #pragma unroll
            for (int c4 = 0; c4 < 4; ++c4) {
                const int cb = half * 4 + c4;
                const int c0 = w * 128 + cb * 16;
                const int g  = c0 >> 8;
                const int wp = (c0 >> 5) & 7;
                const int eb = (c0 >> 4) & 1;
                const int j8 = eb * 4 + g;
                short4v v;
                #pragma unroll
                for (int rr = 0; rr < 4; ++rr) v[rr] = f2bf(acc[rb][c4][rr]);
                *(short4v*)(xz_w +
                    (((size_t)rgg * TCHUNK + tl) * 64 + wp * 8 + j8) * 256 +
                    lane * 4) = v;
            }
        }
    }
}

// ---------------------------------------------------------------------------
// Rec-role: loop-carried weight window (bw lives ACROSS steps; refills for
// i>=4 load next step's groups — same addresses, weights t-invariant) +
// raw barrier (lgkmcnt(0) + s_barrier, NO vmcnt drain). Legal because the
// barrier only needs to order LDS (h dbuf); global loads land in private
// registers. Next-step weight/xz loads stay in flight through the barrier.
// ---------------------------------------------------------------------------
__device__ __forceinline__ void rec_body(
    int rgg, short* smem,
    const short* __restrict__ xz_r, const int* __restrict__ length,
    const short* __restrict__ Wrec, const float* __restrict__ b,
    short* __restrict__ h_state, float* __restrict__ c_state,
    float* __restrict__ xlast, int t0)
{
    const int tid  = threadIdx.x;
    const int w    = tid >> 6;
    const int lane = tid & 63;
    const int lr   = lane & 15;
    const int p    = lane >> 4;
    const int r0   = rgg * BM;

    short (*h_f)[8][512] = (short (*)[8][512])smem;   // [2][8][512], 16 KB
    __shared__ int s_len[BM];
    __shared__ int s_maxlen;

    if (tid < BM) s_len[tid] = length[r0 + tid];
    __syncthreads();
    if (tid == 0) {
        int m = 0;
        for (int r2 = 0; r2 < BM; ++r2) m = max(m, s_len[r2]);
        s_maxlen = m;
    }
    __syncthreads();
    const int mlen = s_maxlen;
    if (mlen <= t0) return;
    const int steps = min(TCHUNK, mlen - t0);

    int len_r[4];
    #pragma unroll
    for (int rr = 0; rr < 4; ++rr) len_r[rr] = s_len[p * 4 + rr];

    float bias[8];
    #pragma unroll
    for (int eb = 0; eb < 2; ++eb)
        #pragma unroll
        for (int g = 0; g < 4; ++g)
            bias[eb * 4 + g] = b[g * 256 + w * 32 + eb * 16 + lr];

    int hoff[2];
    #pragma unroll
    for (int eb = 0; eb < 2; ++eb)
        hoff[eb] = ((eb * 2 + (lr >> 3)) * 16) * 8 + (lr & 7);

    float creg[8];
    if (t0 == 0) {
        for (int i = tid; i < 4096; i += 512) ((int*)h_f)[i] = 0;
        #pragma unroll
        for (int i = 0; i < 8; ++i) creg[i] = 0.f;
    } else {
        #pragma unroll
        for (int eb = 0; eb < 2; ++eb)
            #pragma unroll
            for (int rr = 0; rr < 4; ++rr) {
                const int row = r0 + p * 4 + rr;
                const int e   = w * 32 + eb * 16 + lr;
                creg[eb * 4 + rr] = c_state[(size_t)row * E_DIM + e];
                h_f[0][w][hoff[eb] + (p * 4 + rr) * 8] =
                    h_state[(size_t)row * E_DIM + e];
            }
    }
    __syncthreads();

    const int ph = (rgg >> 3) & 7;
    const short* wthr = Wrec + (size_t)w * 512 + lane * 8;
    const short* xzb  = xz_r + ((size_t)rgg * TCHUNK) * 16384 +
                        (size_t)(w * 8) * 256 + lane * 4;

    // prefetch xz for tl=0
    short4v xv[8];
    #pragma unroll
    for (int j8 = 0; j8 < 8; ++j8)
        xv[j8] = *(const short4v*)(xzb + j8 * 256);

    // loop-carried weight window: groups ph..ph+3
    short8 bw[4][8];
    #pragma unroll
    for (int i = 0; i < 4; ++i) {
        const int kk = (ph + i) & 7;
        #pragma unroll
        for (int j8 = 0; j8 < 8; ++j8)
            bw[i][j8] = *(const short8*)(wthr + (size_t)(kk * 8 + j8) * 4096);
    }

    int cur = 0;
    for (int tl = 0; tl < steps; ++tl) {
        const int t = t0 + tl;

        f32x4 acc[8];
        #pragma unroll
        for (int j8 = 0; j8 < 8; ++j8)
            #pragma unroll
            for (int rr = 0; rr < 4; ++rr)
                acc[j8][rr] = bf2f((unsigned short)xv[j8][rr]);

        // h @ R: 8 kk-groups; refill slot with group needed 4 phases later.
        // For i>=4 the refill targets next step's groups (same addresses).
        #pragma unroll
        for (int i = 0; i < 8; ++i) {
            const int kk = (ph + i) & 7;
            short8 a = *(const short8*)&h_f[cur][kk][lane * 8];
            #pragma unroll
            for (int j8 = 0; j8 < 8; ++j8)
                acc[j8] = __builtin_amdgcn_mfma_f32_16x16x32_bf16(
                    a, bw[i & 3][j8], acc[j8], 0, 0, 0);
            const int kn = (ph + ((i + 4) & 7)) & 7;
            #pragma unroll
            for (int j8 = 0; j8 < 8; ++j8)
                bw[i & 3][j8] = *(const short8*)(wthr + (size_t)(kn * 8 + j8) * 4096);
        }

        // next-step xz prefetch (in flight through the raw barrier)
        if (tl + 1 < steps) {
            #pragma unroll
            for (int j8 = 0; j8 < 8; ++j8)
                xv[j8] = *(const short4v*)(xzb + (size_t)(tl + 1) * 16384 + j8 * 256);
        }

        // gates in registers
        short* hw = &h_f[cur ^ 1][w][0];
        #pragma unroll
        for (int eb = 0; eb < 2; ++eb) {
            #pragma unroll
            for (int rr = 0; rr < 4; ++rr) {
                float zi = acc[eb * 4 + 0][rr] + bias[eb * 4 + 0];
                float zf = acc[eb * 4 + 1][rr] + bias[eb * 4 + 1];
                float zg = acc[eb * 4 + 2][rr] + bias[eb * 4 + 2];
                float zo = acc[eb * 4 + 3][rr] + bias[eb * 4 + 3];
                float ig = sigf(zi), fg = sigf(zf);
                float gg = tanhfast(zg), og = sigf(zo);
                float cc = fg * creg[eb * 4 + rr] + ig * gg;
                float hh = og * tanhfast(cc);
                creg[eb * 4 + rr] = cc;
                const short hb = f2bf(hh);
                hw[hoff[eb] + (p * 4 + rr) * 8] = hb;
                const int row = r0 + p * 4 + rr;
                const int e   = w * 32 + eb * 16 + lr;
                if (t == len_r[rr] - 1)
                    xlast[(size_t)row * E_DIM + e] = hh;
                if (tl == steps - 1) {
                    h_state[(size_t)row * E_DIM + e] = hb;
                    c_state[(size_t)row * E_DIM + e] = cc;
                }
            }
        }
        cur ^= 1;
        // raw barrier: order LDS only; leave global loads in flight.
        asm volatile("s_waitcnt lgkmcnt(0)\n\ts_barrier" ::: "memory");
    }
}

// ---------------------------------------------------------------------------
// Combo: blocks [0, rec_cnt) run rec(chunk c); blocks [rec_cnt, ..) run
// fused(chunk c+1). Independent work -> fused hides under rec's stalls.
// ---------------------------------------------------------------------------
__global__ __launch_bounds__(512, 1) void k_combo(
    const int* __restrict__ code, const float* __restrict__ aux,
    const short* __restrict__ WfL, const float* __restrict__ b_lin,
    const short* __restrict__ WfK,
    const short* __restrict__ Wrec, const float* __restrict__ b,
    const int* __restrict__ length,
    short* __restrict__ h_state, float* __restrict__ c_state,
    float* __restrict__ xlast,
    const short* __restrict__ xz_r, short* __restrict__ xz_w,
    int t0r, int t0f, int rec_cnt)
{
    __shared__ __align__(16) short smem[52224];   // 104448 B shared arena
    const int bid = blockIdx.x;
    if (bid < rec_cnt) {
        rec_body(bid, smem, xz_r, length, Wrec, b,
                 h_state, c_state, xlast, t0r);
    } else if (t0f >= 0) {
        fused_body(bid - rec_cnt, smem, code, aux, WfL, b_lin, WfK,
                   xz_w, t0f);
    }
}

// ---------------------------------------------------------------------------
// Head MLP + L2 normalize (unchanged).
// ---------------------------------------------------------------------------
__global__ __launch_bounds__(256) void k_head(
    const float* __restrict__ xlast,
    const float* __restrict__ W0, const float* __restrict__ b0,
    const float* __restrict__ W1, const float* __restrict__ b1,
    float* __restrict__ out)
{
    const int n = blockIdx.x;
    const int j = threadIdx.x;

    __shared__ __align__(16) float xsh[E_DIM];
    __shared__ __align__(16) float y0[E_DIM];
    __shared__ float part[4];

    xsh[j] = xlast[(size_t)n * E_DIM + j];
    __syncthreads();

    float acc = b0[j];
    for (int k4 = 0; k4 < E_DIM; k4 += 4) {
        float4 xv = *reinterpret_cast<const float4*>(&xsh[k4]);
        #pragma unroll
        for (int kk = 0; kk < 4; ++kk)
            acc += (&xv.x)[kk] * W0[(size_t)(k4 + kk) * E_DIM + j];
    }
    y0[j] = fmaxf(acc, 0.f);
    __syncthreads();

    acc = b1[j];
    for (int k4 = 0; k4 < E_DIM; k4 += 4) {
        float4 yv = *reinterpret_cast<const float4*>(&y0[k4]);
        #pragma unroll
        for (int kk = 0; kk < 4; ++kk)
            acc += (&yv.x)[kk] * W1[(size_t)(k4 + kk) * E_DIM + j];
    }

    float sq = acc * acc;
    #pragma unroll
    for (int off = 32; off > 0; off >>= 1)
        sq += __shfl_xor(sq, off, 64);
    if ((j & 63) == 0) part[j >> 6] = sq;
    __syncthreads();
    float total = part[0] + part[1] + part[2] + part[3];

    out[(size_t)n * E_DIM + j] = acc * rsqrtf(total);
}

// ---------------------------------------------------------------------------
extern "C" void kernel_launch(void* const* d_in, const int* in_sizes, int n_in,
                              void* d_out, int out_size, void* d_ws, size_t ws_size,
                              hipStream_t stream) {
    const int*   code   = (const int*)  d_in[0];
    const float* aux    = (const float*)d_in[1];
    const int*   length = (const int*)  d_in[2];
    // d_in[3] = is_training (ignored)
    const float* W_lin  = (const float*)d_in[4];
    const float* b_lin  = (const float*)d_in[5];
    const float* K      = (const float*)d_in[6];
    const float* R      = (const float*)d_in[7];
    const float* b      = (const float*)d_in[8];
    const float* W0     = (const float*)d_in[9];
    const float* b0     = (const float*)d_in[10];
    const float* W1     = (const float*)d_in[11];
    const float* b1     = (const float*)d_in[12];
    float* out = (float*)d_out;

    // workspace layout (bytes, 16B aligned); total ~90.5 MB
    char* ws = (char*)d_ws;
    short* Wrec    = (short*)(ws + 0);            //    524,288
    short* WfK     = (short*)(ws + 524288);       //    524,288
    short* WfL     = (short*)(ws + 1048576);      //    278,528
    float* xlast   = (float*)(ws + 1327104);      //  2,097,152
    short* h_state = (short*)(ws + 3424256);      //  1,048,576
    float* c_state = (float*)(ws + 4472832);      //  2,097,152
    short* xzp0    = (short*)(ws + 6569984);      // 41,943,040
    short* xzp1    = (short*)(ws + 48513024);     // 41,943,040

    k_prep_wrec<<<128, 256, 0, stream>>>(R, Wrec);
    k_prep_wfk <<<128, 256, 0, stream>>>(K, WfK);
    k_prep_wfl <<<68,  256, 0, stream>>>(W_lin, WfL);

    short* xzbuf[2] = {xzp0, xzp1};

    // d1: fused-only for chunk 0 -> xzp0
    k_combo<<<NFUSED, 512, 0, stream>>>(
        code, aux, WfL, b_lin, WfK, Wrec, b, length,
        h_state, c_state, xlast, xzp0, xzp0, 0, 0, 0);

    // d2..d5: rec(chunk c) + fused(chunk c+1)
    for (int c = 0; c < 4; ++c) {
        k_combo<<<128 + NFUSED, 512, 0, stream>>>(
            code, aux, WfL, b_lin, WfK, Wrec, b, length,
            h_state, c_state, xlast,
            xzbuf[c & 1], xzbuf[(c + 1) & 1],
            c * TCHUNK, (c + 1) * TCHUNK, 128);
    }
    // d6: rec-only for chunk 4
    k_combo<<<128, 512, 0, stream>>>(
        code, aux, WfL, b_lin, WfK, Wrec, b, length,
        h_state, c_state, xlast, xzbuf[0], xzbuf[0],
        4 * TCHUNK, -1, 128);

    k_head<<<N_BATCH, 256, 0, stream>>>(xlast, W0, b0, W1, b1, out);
}